// Round 1
// baseline (409.263 us; speedup 1.0000x reference)
//
#include <hip/hip_runtime.h>

#define NVEC   131072      // 32*64*64 vectors
#define DIM    64
#define KCODES 512
#define HW     4096        // 64*64
#define CHW    262144      // 64*4096
#define QOFF   1
#define PERPOFF 8388609    // 1 + 32*64*64*64
#define ENCOFF  8388610

// ws layout (bytes):
//   0       : int counts[512]            (2048 B)
//   2048    : double loss_acc            (8 B)
//   4096    : double wsq[512]            (4096 B)
//   8192    : double wd[512*64]          (262144 B)
//   270336  : int idx[131072]            (524288 B)
// total ~776 KB

__global__ __launch_bounds__(512) void vq_init(int* __restrict__ counts,
                                               double* __restrict__ loss) {
    int t = threadIdx.x;
    counts[t] = 0;
    if (t == 0) loss[0] = 0.0;
}

// Convert weight to f64, compute ||w||^2 per code in f64.
__global__ __launch_bounds__(64) void vq_prep(const float* __restrict__ wt,
                                              double* __restrict__ wd,
                                              double* __restrict__ wsq) {
    int c = blockIdx.x, d = threadIdx.x;
    double v = (double)wt[c * 64 + d];
    wd[c * 64 + d] = v;
    double s = v * v;
    for (int off = 32; off; off >>= 1) s += __shfl_down(s, off, 64);
    if (d == 0) wsq[c] = s;
}

// One thread per input vector: f64-exact argmin over 512 codes,
// write quantized_st (NCHW), per-block histogram + loss partial.
__global__ __launch_bounds__(256) void vq_assign(
    const float* __restrict__ x, const float* __restrict__ wt,
    const double* __restrict__ wd, const double* __restrict__ wsq,
    float* __restrict__ out, int* __restrict__ idx,
    int* __restrict__ counts, double* __restrict__ loss_acc)
{
    int n = blockIdx.x * 256 + threadIdx.x;          // 0..131071
    int b = n >> 12;
    int rem = n & 4095;                              // h*64 + w
    const float* xp = x + (size_t)b * CHW + rem;

    double xd[64];
#pragma unroll
    for (int d = 0; d < 64; ++d) xd[d] = (double)xp[(size_t)d * HW];

    double best = 1e300; int bestc = 0;
    for (int c = 0; c < 512; ++c) {
        const double* wr = wd + c * 64;
        double a0 = 0, a1 = 0, a2 = 0, a3 = 0;
#pragma unroll
        for (int d = 0; d < 64; d += 4) {
            a0 = __fma_rn(xd[d + 0], wr[d + 0], a0);
            a1 = __fma_rn(xd[d + 1], wr[d + 1], a1);
            a2 = __fma_rn(xd[d + 2], wr[d + 2], a2);
            a3 = __fma_rn(xd[d + 3], wr[d + 3], a3);
        }
        double dist = wsq[c] - 2.0 * ((a0 + a1) + (a2 + a3));
        if (dist < best) { best = dist; bestc = c; } // strict < => first index on ties
    }
    idx[n] = bestc;

    // epilogue: quantized_st in reference f32 op order + loss partial
    const float* qw = wt + bestc * 64;
    float* op = out + QOFF + (size_t)b * CHW + rem;
    float lsum = 0.f;
#pragma unroll
    for (int d = 0; d < 64; ++d) {
        float xf = (float)xd[d];       // exact round-trip of original f32
        float qf = qw[d];
        float diff = qf - xf;
        lsum += diff * diff;
        op[(size_t)d * HW] = xf + diff;
    }

    // block histogram in LDS
    __shared__ int hc[512];
    hc[threadIdx.x] = 0; hc[threadIdx.x + 256] = 0;
    __syncthreads();
    atomicAdd(&hc[bestc], 1);

    // loss reduction: wave shuffle (f64) -> LDS -> one atomic per block
    double ls = (double)lsum;
    for (int off = 32; off; off >>= 1) ls += __shfl_down(ls, off, 64);
    __shared__ double lred[4];
    int wave = threadIdx.x >> 6, lane = threadIdx.x & 63;
    if (lane == 0) lred[wave] = ls;
    __syncthreads();
    if (threadIdx.x == 0)
        atomicAdd(loss_acc, (lred[0] + lred[1]) + (lred[2] + lred[3]));

    int v0 = hc[threadIdx.x], v1 = hc[threadIdx.x + 256];
    if (v0) atomicAdd(&counts[threadIdx.x], v0);
    if (v1) atomicAdd(&counts[threadIdx.x + 256], v1);
}

// Fill one-hot encodings [N,512] f32. float2 stores (region is 8B-aligned only).
__global__ __launch_bounds__(256) void vq_enc(const int* __restrict__ idx,
                                              float2* __restrict__ enc) {
    int gid = blockIdx.x * 256 + threadIdx.x;   // 33,554,432 threads total
    int row = gid >> 8;                          // 256 float2 per row
    int pos = (gid & 255) << 1;
    int id = idx[row];
    float2 v;
    v.x = (id == pos)     ? 1.f : 0.f;
    v.y = (id == pos + 1) ? 1.f : 0.f;
    enc[gid] = v;
}

__global__ __launch_bounds__(512) void vq_fin(const int* __restrict__ counts,
                                              const double* __restrict__ loss_acc,
                                              float* __restrict__ out) {
    __shared__ double red[512];
    int k = threadIdx.x;
    double p = (double)counts[k] * (1.0 / 131072.0);
    red[k] = p * log(p + 1e-10);   // p==0 -> 0, matches reference
    __syncthreads();
    for (int s = 256; s; s >>= 1) {
        if (k < s) red[k] += red[k + s];
        __syncthreads();
    }
    if (k == 0) {
        out[PERPOFF] = (float)exp(-red[0]);
        out[0] = (float)(loss_acc[0] * 1.25 / 8388608.0);
    }
}

extern "C" void kernel_launch(void* const* d_in, const int* in_sizes, int n_in,
                              void* d_out, int out_size, void* d_ws, size_t ws_size,
                              hipStream_t stream) {
    const float* x  = (const float*)d_in[0];
    const float* wt = (const float*)d_in[1];
    float* out = (float*)d_out;
    char* ws = (char*)d_ws;

    int*    counts = (int*)ws;
    double* loss   = (double*)(ws + 2048);
    double* wsq    = (double*)(ws + 4096);
    double* wd     = (double*)(ws + 8192);
    int*    idx    = (int*)(ws + 270336);

    vq_init<<<1, 512, 0, stream>>>(counts, loss);
    vq_prep<<<KCODES, 64, 0, stream>>>(wt, wd, wsq);
    vq_assign<<<NVEC / 256, 256, 0, stream>>>(x, wt, wd, wsq, out, idx, counts, loss);
    vq_enc<<<131072, 256, 0, stream>>>(idx, (float2*)(out + ENCOFF));
    vq_fin<<<1, 512, 0, stream>>>(counts, loss, out);
}

// Round 2
// 367.319 us; speedup vs baseline: 1.1142x; 1.1142x over previous
//
#include <hip/hip_runtime.h>

#define NVEC   131072      // 32*64*64 vectors
#define DIM    64
#define KCODES 512
#define HW     4096        // 64*64
#define CHW    262144      // 64*4096
#define QOFF   1
#define PERPOFF 8388609    // 1 + 32*64*64*64
#define ENCOFF  8388610

// ws layout (bytes):
//   0    : int counts[512]   (2048 B)
//   2048 : double loss_acc   (8 B)
//   4096 : float wsq[512]    (2048 B)

__global__ __launch_bounds__(512) void vq_init(int* __restrict__ counts,
                                               double* __restrict__ loss) {
    int t = threadIdx.x;
    counts[t] = 0;
    if (t == 0) loss[0] = 0.0;
}

__global__ __launch_bounds__(64) void vq_prep(const float* __restrict__ wt,
                                              float* __restrict__ wsq) {
    int c = blockIdx.x, d = threadIdx.x;
    float v = wt[c * 64 + d];
    float s = v * v;
    for (int off = 32; off; off >>= 1) s += __shfl_down(s, off, 64);
    if (d == 0) wsq[c] = s;
}

// 256 blocks x 256 threads, 2 vectors per thread.
// f32 argmin over 512 codes (W staged in LDS, 128-code tiles),
// writes quantized_st (NCHW), scatters one-hot 1.0f, histogram + loss.
__global__ __launch_bounds__(256, 1) void vq_assign(
    const float* __restrict__ x, const float* __restrict__ wt,
    const float* __restrict__ wsq,
    float* __restrict__ out, float* __restrict__ enc,
    int* __restrict__ counts, double* __restrict__ loss_acc)
{
    __shared__ float wl[128 * 64];     // 32 KB code tile
    __shared__ float wsql[128];
    __shared__ int   hc[512];
    __shared__ double lred[4];

    const int t = threadIdx.x, b = blockIdx.x;
    const int batch = b >> 3;
    const int pos0  = ((b & 7) << 9) + t;          // vec0 pos; vec1 = pos0+256
    const float* xp = x + (size_t)batch * CHW + pos0;

    // load 2 vectors into registers (coalesced: lanes = consecutive pos)
    float x0[64], x1[64];
#pragma unroll
    for (int d = 0; d < 64; ++d) {
        x0[d] = xp[(size_t)d * HW];
        x1[d] = xp[(size_t)d * HW + 256];
    }

    float best0 = 1e30f, best1 = 1e30f;
    int   bc0 = 0, bc1 = 0;

    for (int tile = 0; tile < 4; ++tile) {
        __syncthreads();
        // stage 128 codes (8192 floats) into LDS, coalesced float4
        const float4* src = (const float4*)(wt + tile * 128 * 64);
        float4* dst = (float4*)wl;
#pragma unroll
        for (int i = 0; i < 8; ++i) dst[t + 256 * i] = src[t + 256 * i];
        if (t < 128) wsql[t] = wsq[tile * 128 + t];
        __syncthreads();

        for (int c = 0; c < 128; ++c) {
            const float4* wr = (const float4*)(wl + c * 64);
            float a0 = 0.f, a1 = 0.f, a2 = 0.f, a3 = 0.f;
            float b0 = 0.f, b1 = 0.f, b2 = 0.f, b3 = 0.f;
#pragma unroll
            for (int k = 0; k < 16; ++k) {
                float4 wv = wr[k];
                a0 = fmaf(x0[4 * k + 0], wv.x, a0);
                a1 = fmaf(x0[4 * k + 1], wv.y, a1);
                a2 = fmaf(x0[4 * k + 2], wv.z, a2);
                a3 = fmaf(x0[4 * k + 3], wv.w, a3);
                b0 = fmaf(x1[4 * k + 0], wv.x, b0);
                b1 = fmaf(x1[4 * k + 1], wv.y, b1);
                b2 = fmaf(x1[4 * k + 2], wv.z, b2);
                b3 = fmaf(x1[4 * k + 3], wv.w, b3);
            }
            float wq = wsql[c];
            float d0 = fmaf(-2.f, (a0 + a1) + (a2 + a3), wq);
            float d1 = fmaf(-2.f, (b0 + b1) + (b2 + b3), wq);
            int cg = tile * 128 + c;
            if (d0 < best0) { best0 = d0; bc0 = cg; }
            if (d1 < best1) { best1 = d1; bc1 = cg; }
        }
    }

    // ---- epilogue ----
    // quantized_st + loss partial (gather the two winning code rows)
    const float4* qw0 = (const float4*)(wt + bc0 * 64);
    const float4* qw1 = (const float4*)(wt + bc1 * 64);
    float* op = out + QOFF + (size_t)batch * CHW + pos0;
    float ls = 0.f;
#pragma unroll
    for (int k = 0; k < 16; ++k) {
        float4 q0 = qw0[k];
        float4 q1 = qw1[k];
#pragma unroll
        for (int j = 0; j < 4; ++j) {
            int d = 4 * k + j;
            float qa = (j == 0) ? q0.x : (j == 1) ? q0.y : (j == 2) ? q0.z : q0.w;
            float qb = (j == 0) ? q1.x : (j == 1) ? q1.y : (j == 2) ? q1.z : q1.w;
            float da = qa - x0[d];
            float db = qb - x1[d];
            ls += da * da + db * db;
            op[(size_t)d * HW]       = x0[d] + da;
            op[(size_t)d * HW + 256] = x1[d] + db;
        }
    }

    // one-hot scatter (region pre-zeroed by hipMemsetAsync)
    size_t n0 = (size_t)b * 512 + t;
    enc[n0 * 512 + bc0] = 1.0f;
    enc[(n0 + 256) * 512 + bc1] = 1.0f;

    // block histogram
    hc[t] = 0; hc[t + 256] = 0;
    __syncthreads();
    atomicAdd(&hc[bc0], 1);
    atomicAdd(&hc[bc1], 1);

    // loss reduction: wave shuffle (f64) -> LDS -> one atomic per block
    double lsd = (double)ls;
    for (int off = 32; off; off >>= 1) lsd += __shfl_down(lsd, off, 64);
    int wave = t >> 6, lane = t & 63;
    if (lane == 0) lred[wave] = lsd;
    __syncthreads();
    if (t == 0)
        atomicAdd(loss_acc, (lred[0] + lred[1]) + (lred[2] + lred[3]));

    int v0 = hc[t], v1 = hc[t + 256];
    if (v0) atomicAdd(&counts[t], v0);
    if (v1) atomicAdd(&counts[t + 256], v1);
}

__global__ __launch_bounds__(512) void vq_fin(const int* __restrict__ counts,
                                              const double* __restrict__ loss_acc,
                                              float* __restrict__ out) {
    __shared__ double red[512];
    int k = threadIdx.x;
    double p = (double)counts[k] * (1.0 / 131072.0);
    red[k] = p * log(p + 1e-10);   // p==0 -> 0, matches reference
    __syncthreads();
    for (int s = 256; s; s >>= 1) {
        if (k < s) red[k] += red[k + s];
        __syncthreads();
    }
    if (k == 0) {
        out[PERPOFF] = (float)exp(-red[0]);
        out[0] = (float)(loss_acc[0] * 1.25 / 8388608.0);
    }
}

extern "C" void kernel_launch(void* const* d_in, const int* in_sizes, int n_in,
                              void* d_out, int out_size, void* d_ws, size_t ws_size,
                              hipStream_t stream) {
    const float* x  = (const float*)d_in[0];
    const float* wt = (const float*)d_in[1];
    float* out = (float*)d_out;
    char* ws = (char*)d_ws;

    int*    counts = (int*)ws;
    double* loss   = (double*)(ws + 2048);
    float*  wsq    = (float*)(ws + 4096);
    float*  enc    = out + ENCOFF;

    vq_init<<<1, 512, 0, stream>>>(counts, loss);
    vq_prep<<<KCODES, 64, 0, stream>>>(wt, wsq);
    // zero the one-hot region (268435456 B); assign scatters the 1.0s
    hipMemsetAsync((void*)enc, 0, (size_t)NVEC * KCODES * sizeof(float), stream);
    vq_assign<<<NVEC / 512, 256, 0, stream>>>(x, wt, wsq, out, enc, counts, loss);
    vq_fin<<<1, 512, 0, stream>>>(counts, loss, out);
}

// Round 4
// 110.300 us; speedup vs baseline: 3.7105x; 3.3302x over previous
//
#include <hip/hip_runtime.h>

typedef short   bf16x8 __attribute__((ext_vector_type(8)));
typedef float   f32x4  __attribute__((ext_vector_type(4)));
typedef float   f32x2  __attribute__((ext_vector_type(2)));

#define NVEC   131072      // 32*64*64 vectors
#define HW     4096
#define CHW    262144
#define QOFF   1
#define PERPOFF 8388609
#define ENCOFF  8388610

// ws layout: counts[512] @0, double loss @2048, float bias[512] @4096,
//            ushort wbf[512*64] @8192 (64 KB)

__device__ inline unsigned short f2bf(float f) {   // RTNE float->bf16
    unsigned int u = __float_as_uint(f);
    u += 0x7fffu + ((u >> 16) & 1u);
    return (unsigned short)(u >> 16);
}

__global__ __launch_bounds__(512) void vq_init(int* __restrict__ counts,
                                               double* __restrict__ loss) {
    int t = threadIdx.x;
    counts[t] = 0;
    if (t == 0) loss[0] = 0.0;
}

// per code: bf16 copy of W + bias = -0.5*||w||^2 (f32-exact)
__global__ __launch_bounds__(64) void vq_prep(const float* __restrict__ wt,
                                              float* __restrict__ bias,
                                              unsigned short* __restrict__ wbf) {
    int c = blockIdx.x, d = threadIdx.x;
    float v = wt[c * 64 + d];
    wbf[c * 64 + d] = f2bf(v);
    float s = v * v;
    for (int off = 32; off; off >>= 1) s += __shfl_down(s, off, 64);
    if (d == 0) bias[c] = -0.5f * s;
}

// 512 blocks x 256 threads. Wave handles 64 rows (pos), 4 row-sets of 16.
// Scores via mfma_f32_16x16x32_bf16 with C preloaded = -wsq/2; argmax.
__global__ __launch_bounds__(256, 2) void vq_assign(
    const float* __restrict__ x, const float* __restrict__ wt,
    const float* __restrict__ bias, const unsigned short* __restrict__ wbf,
    float* __restrict__ out, int* __restrict__ counts,
    double* __restrict__ loss_acc)
{
    __shared__ unsigned short wl[512 * 64];   // 64 KB, XOR-swizzled rows
    __shared__ float  biasl[512];
    __shared__ int    hc[512];
    __shared__ int    winners[256];
    __shared__ double lred[4];

    const int t = threadIdx.x, b = blockIdx.x;
    const int batch  = b >> 4;
    const int posblk = (b & 15) << 8;

    // ---- stage W bf16 into LDS with st-swizzle (row c: byte ^= (c&7)<<4) ----
    {
        const ulonglong2* src = (const ulonglong2*)wbf;   // 16B units
#pragma unroll
        for (int i = 0; i < 16; ++i) {
            int u  = t + 256 * i;          // 16B-unit index, 0..4095
            int c  = u >> 3;               // code row
            int bo = (u & 7) << 4;         // byte-in-row
            ulonglong2 v = src[u];
            *(ulonglong2*)((char*)wl + ((c << 7) | (bo ^ ((c & 7) << 4)))) = v;
        }
        biasl[t] = bias[t]; biasl[t + 256] = bias[t + 256];
        hc[t] = 0; hc[t + 256] = 0;
    }
    __syncthreads();

    const int wv = t >> 6, l = t & 63;
    const int g  = l >> 4, cl = l & 15;
    const int posw = posblk + (wv << 6);      // this wave's 64 pos
    const int d0 = g << 3;

    // ---- load X f32 directly in A-fragment layout ----
    // lane: pos = posw + 16s + cl, d in {d0..d0+7} u {32+d0..32+d0+7}
    float xs[4][16];
    const float* xb = x + (size_t)batch * CHW + posw + cl;
#pragma unroll
    for (int s = 0; s < 4; ++s)
#pragma unroll
        for (int j = 0; j < 8; ++j) {
            xs[s][j]     = xb[(size_t)(d0 + j) * HW + 16 * s];
            xs[s][j + 8] = xb[(size_t)(32 + d0 + j) * HW + 16 * s];
        }

    bf16x8 af[4][2];
#pragma unroll
    for (int s = 0; s < 4; ++s)
#pragma unroll
        for (int h = 0; h < 2; ++h)
#pragma unroll
            for (int i = 0; i < 8; ++i)
                af[s][h][i] = (short)f2bf(xs[s][8 * h + i]);

    // ---- score loop: 32 col-tiles of 16 codes ----
    float best[4][4]; int bidx[4][4];
#pragma unroll
    for (int s = 0; s < 4; ++s)
#pragma unroll
        for (int i = 0; i < 4; ++i) { best[s][i] = -1e30f; bidx[s][i] = 0; }

    const char* wlb = (const char*)wl;
#pragma unroll 4
    for (int tt = 0; tt < 32; ++tt) {
        int c  = (tt << 4) + cl;
        int rb = c << 7;
        int sw = (c & 7) << 4;
        bf16x8 b0 = *(const bf16x8*)(wlb + (rb | ((16 * g) ^ sw)));
        bf16x8 b1 = *(const bf16x8*)(wlb + (rb | ((64 + 16 * g) ^ sw)));
        float bs = biasl[c];
#pragma unroll
        for (int s = 0; s < 4; ++s) {
            f32x4 acc = {bs, bs, bs, bs};
            acc = __builtin_amdgcn_mfma_f32_16x16x32_bf16(af[s][0], b0, acc, 0, 0, 0);
            acc = __builtin_amdgcn_mfma_f32_16x16x32_bf16(af[s][1], b1, acc, 0, 0, 0);
#pragma unroll
            for (int i = 0; i < 4; ++i)
                if (acc[i] > best[s][i]) { best[s][i] = acc[i]; bidx[s][i] = c; }
        }
    }

    // ---- 16-lane butterfly argmax (tie -> smaller index) ----
#pragma unroll
    for (int s = 0; s < 4; ++s)
#pragma unroll
        for (int i = 0; i < 4; ++i) {
            float bd = best[s][i]; int bi = bidx[s][i];
#pragma unroll
            for (int off = 1; off < 16; off <<= 1) {
                float od = __shfl_xor(bd, off, 64);
                int   oi = __shfl_xor(bi, off, 64);
                if (od > bd || (od == bd && oi < bi)) { bd = od; bi = oi; }
            }
            bidx[s][i] = bi;
        }

    // winners to LDS (row-in-wave = 16s + 4g + i), + histogram
    if (cl == 0) {
#pragma unroll
        for (int s = 0; s < 4; ++s)
#pragma unroll
            for (int i = 0; i < 4; ++i) {
                int w = bidx[s][i];
                winners[(wv << 6) + (s << 4) + (g << 2) + i] = w;
                atomicAdd(&hc[w], 1);
            }
    }
    __syncthreads();

    // ---- epilogue: quantized_st + loss (f32-exact), one-hot rows ----
    float* outb = out + QOFF + (size_t)batch * CHW + posw + cl;
    float ls = 0.f;
#pragma unroll
    for (int s = 0; s < 4; ++s) {
        int widx = winners[(wv << 6) + (s << 4) + cl];
        float q[16];
        *(float4*)&q[0]  = *(const float4*)(wt + widx * 64 + d0);
        *(float4*)&q[4]  = *(const float4*)(wt + widx * 64 + d0 + 4);
        *(float4*)&q[8]  = *(const float4*)(wt + widx * 64 + 32 + d0);
        *(float4*)&q[12] = *(const float4*)(wt + widx * 64 + 32 + d0 + 4);
#pragma unroll
        for (int j = 0; j < 8; ++j) {
            float da = q[j]     - xs[s][j];
            float db = q[j + 8] - xs[s][j + 8];
            ls += da * da + db * db;
            outb[(size_t)(d0 + j) * HW + 16 * s]      = xs[s][j]     + da;
            outb[(size_t)(32 + d0 + j) * HW + 16 * s] = xs[s][j + 8] + db;
        }
    }

    // one-hot: 64 rows x 512 f32, f32x2 stores (region 8B-aligned)
    {
        f32x2* encp = (f32x2*)(out + ENCOFF);
        size_t nbase = (size_t)batch * 4096 + posw;
#pragma unroll 2
        for (int r = 0; r < 64; ++r) {
            int widx = winners[(wv << 6) + r];
            size_t rowb = (nbase + r) * 256;          // f32x2 units/row
#pragma unroll
            for (int h = 0; h < 4; ++h) {
                int c0 = (h << 7) + (l << 1);
                f32x2 v;
                v.x = (widx == c0)     ? 1.f : 0.f;
                v.y = (widx == c0 + 1) ? 1.f : 0.f;
                __builtin_nontemporal_store(v, &encp[rowb + (c0 >> 1)]);
            }
        }
    }

    // ---- loss reduction ----
    double lsd = (double)ls;
    for (int off = 32; off; off >>= 1) lsd += __shfl_down(lsd, off, 64);
    if (l == 0) lred[wv] = lsd;
    __syncthreads();
    if (t == 0)
        atomicAdd(loss_acc, (lred[0] + lred[1]) + (lred[2] + lred[3]));

    int v0 = hc[t], v1 = hc[t + 256];
    if (v0) atomicAdd(&counts[t], v0);
    if (v1) atomicAdd(&counts[t + 256], v1);
}

__global__ __launch_bounds__(512) void vq_fin(const int* __restrict__ counts,
                                              const double* __restrict__ loss_acc,
                                              float* __restrict__ out) {
    __shared__ double red[512];
    int k = threadIdx.x;
    double p = (double)counts[k] * (1.0 / 131072.0);
    red[k] = p * log(p + 1e-10);
    __syncthreads();
    for (int s = 256; s; s >>= 1) {
        if (k < s) red[k] += red[k + s];
        __syncthreads();
    }
    if (k == 0) {
        out[PERPOFF] = (float)exp(-red[0]);
        out[0] = (float)(loss_acc[0] * 1.25 / 8388608.0);
    }
}

extern "C" void kernel_launch(void* const* d_in, const int* in_sizes, int n_in,
                              void* d_out, int out_size, void* d_ws, size_t ws_size,
                              hipStream_t stream) {
    const float* x  = (const float*)d_in[0];
    const float* wt = (const float*)d_in[1];
    float* out = (float*)d_out;
    char* ws = (char*)d_ws;

    int*            counts = (int*)ws;
    double*         loss   = (double*)(ws + 2048);
    float*          bias   = (float*)(ws + 4096);
    unsigned short* wbf    = (unsigned short*)(ws + 8192);

    vq_init<<<1, 512, 0, stream>>>(counts, loss);
    vq_prep<<<512, 64, 0, stream>>>(wt, bias, wbf);
    vq_assign<<<512, 256, 0, stream>>>(x, wt, bias, wbf, out, counts, loss);
    vq_fin<<<1, 512, 0, stream>>>(counts, loss, out);
}

// Round 5
// 100.563 us; speedup vs baseline: 4.0697x; 1.0968x over previous
//
#include <hip/hip_runtime.h>

typedef short   bf16x8 __attribute__((ext_vector_type(8)));
typedef float   f32x4  __attribute__((ext_vector_type(4)));

#define NVEC   131072      // 32*64*64 vectors
#define HW     4096
#define CHW    262144
#define QOFF   1
#define PERPOFF 8388609
#define ENCOFF  8388610

// ws layout: counts[512] @0, double loss @2048, float bias[512] @4096,
//            ushort wbf[512*64] @8192 (64 KB)

__device__ inline unsigned short f2bf(float f) {   // RTNE float->bf16
    unsigned int u = __float_as_uint(f);
    u += 0x7fffu + ((u >> 16) & 1u);
    return (unsigned short)(u >> 16);
}

// per code: bf16 copy of W + bias = -0.5*||w||^2 (f32-exact).
// Block 0 additionally zeroes counts + loss.
__global__ __launch_bounds__(64) void vq_prep(const float* __restrict__ wt,
                                              float* __restrict__ bias,
                                              unsigned short* __restrict__ wbf,
                                              int* __restrict__ counts,
                                              double* __restrict__ loss) {
    int c = blockIdx.x, d = threadIdx.x;
    if (c == 0) {
#pragma unroll
        for (int i = 0; i < 8; ++i) counts[d * 8 + i] = 0;
        if (d == 0) loss[0] = 0.0;
    }
    float v = wt[c * 64 + d];
    wbf[c * 64 + d] = f2bf(v);
    float s = v * v;
    for (int off = 32; off; off >>= 1) s += __shfl_down(s, off, 64);
    if (d == 0) bias[c] = -0.5f * s;
}

// 512 blocks x 256 threads. Wave handles 64 rows (pos), 4 row-sets of 16.
// Scores via mfma_f32_16x16x32_bf16 with C preloaded = -wsq/2; argmax.
// One-hot region pre-zeroed by memset; we scatter the 1.0s here.
__global__ __launch_bounds__(256, 2) void vq_assign(
    const float* __restrict__ x, const float* __restrict__ wt,
    const float* __restrict__ bias, const unsigned short* __restrict__ wbf,
    float* __restrict__ out, float* __restrict__ enc,
    int* __restrict__ counts, double* __restrict__ loss_acc)
{
    __shared__ unsigned short wl[512 * 64];   // 64 KB, XOR-swizzled rows
    __shared__ float  biasl[512];
    __shared__ int    hc[512];
    __shared__ int    winners[256];
    __shared__ double lred[4];

    const int t = threadIdx.x, b = blockIdx.x;
    const int batch  = b >> 4;
    const int posblk = (b & 15) << 8;

    // ---- stage W bf16 into LDS with st-swizzle (row c: byte ^= (c&7)<<4) ----
    {
        const ulonglong2* src = (const ulonglong2*)wbf;   // 16B units
#pragma unroll
        for (int i = 0; i < 16; ++i) {
            int u  = t + 256 * i;          // 16B-unit index, 0..4095
            int c  = u >> 3;               // code row
            int bo = (u & 7) << 4;         // byte-in-row
            ulonglong2 v = src[u];
            *(ulonglong2*)((char*)wl + ((c << 7) | (bo ^ ((c & 7) << 4)))) = v;
        }
        biasl[t] = bias[t]; biasl[t + 256] = bias[t + 256];
        hc[t] = 0; hc[t + 256] = 0;
    }
    __syncthreads();

    const int wv = t >> 6, l = t & 63;
    const int g  = l >> 4, cl = l & 15;
    const int posw = posblk + (wv << 6);      // this wave's 64 pos
    const int d0 = g << 3;

    // ---- load X f32 directly in A-fragment layout ----
    // lane: pos = posw + 16s + cl, d in {d0..d0+7} u {32+d0..32+d0+7}
    float xs[4][16];
    const float* xb = x + (size_t)batch * CHW + posw + cl;
#pragma unroll
    for (int s = 0; s < 4; ++s)
#pragma unroll
        for (int j = 0; j < 8; ++j) {
            xs[s][j]     = xb[(size_t)(d0 + j) * HW + 16 * s];
            xs[s][j + 8] = xb[(size_t)(32 + d0 + j) * HW + 16 * s];
        }

    bf16x8 af[4][2];
#pragma unroll
    for (int s = 0; s < 4; ++s)
#pragma unroll
        for (int h = 0; h < 2; ++h)
#pragma unroll
            for (int i = 0; i < 8; ++i)
                af[s][h][i] = (short)f2bf(xs[s][8 * h + i]);

    // ---- score loop: 32 col-tiles of 16 codes ----
    float best[4][4]; int bidx[4][4];
#pragma unroll
    for (int s = 0; s < 4; ++s)
#pragma unroll
        for (int i = 0; i < 4; ++i) { best[s][i] = -1e30f; bidx[s][i] = 0; }

    const char* wlb = (const char*)wl;
#pragma unroll 4
    for (int tt = 0; tt < 32; ++tt) {
        int c  = (tt << 4) + cl;
        int rb = c << 7;
        int sw = (c & 7) << 4;
        bf16x8 b0 = *(const bf16x8*)(wlb + (rb | ((16 * g) ^ sw)));
        bf16x8 b1 = *(const bf16x8*)(wlb + (rb | ((64 + 16 * g) ^ sw)));
        float bs = biasl[c];
#pragma unroll
        for (int s = 0; s < 4; ++s) {
            f32x4 acc = {bs, bs, bs, bs};
            acc = __builtin_amdgcn_mfma_f32_16x16x32_bf16(af[s][0], b0, acc, 0, 0, 0);
            acc = __builtin_amdgcn_mfma_f32_16x16x32_bf16(af[s][1], b1, acc, 0, 0, 0);
#pragma unroll
            for (int i = 0; i < 4; ++i)
                if (acc[i] > best[s][i]) { best[s][i] = acc[i]; bidx[s][i] = c; }
        }
    }

    // ---- 16-lane butterfly argmax (tie -> smaller index) ----
#pragma unroll
    for (int s = 0; s < 4; ++s)
#pragma unroll
        for (int i = 0; i < 4; ++i) {
            float bd = best[s][i]; int bi = bidx[s][i];
#pragma unroll
            for (int off = 1; off < 16; off <<= 1) {
                float od = __shfl_xor(bd, off, 64);
                int   oi = __shfl_xor(bi, off, 64);
                if (od > bd || (od == bd && oi < bi)) { bd = od; bi = oi; }
            }
            bidx[s][i] = bi;
        }

    // winners to LDS (row-in-wave = 16s + 4g + i), + histogram
    if (cl == 0) {
#pragma unroll
        for (int s = 0; s < 4; ++s)
#pragma unroll
            for (int i = 0; i < 4; ++i) {
                int w = bidx[s][i];
                winners[(wv << 6) + (s << 4) + (g << 2) + i] = w;
                atomicAdd(&hc[w], 1);
            }
    }
    __syncthreads();

    // ---- epilogue: quantized_st + loss (f32-exact) ----
    float* outb = out + QOFF + (size_t)batch * CHW + posw + cl;
    float ls = 0.f;
#pragma unroll
    for (int s = 0; s < 4; ++s) {
        int widx = winners[(wv << 6) + (s << 4) + cl];
        float q[16];
        *(float4*)&q[0]  = *(const float4*)(wt + widx * 64 + d0);
        *(float4*)&q[4]  = *(const float4*)(wt + widx * 64 + d0 + 4);
        *(float4*)&q[8]  = *(const float4*)(wt + widx * 64 + 32 + d0);
        *(float4*)&q[12] = *(const float4*)(wt + widx * 64 + 32 + d0 + 4);
#pragma unroll
        for (int j = 0; j < 8; ++j) {
            float da = q[j]     - xs[s][j];
            float db = q[j + 8] - xs[s][j + 8];
            ls += da * da + db * db;
            outb[(size_t)(d0 + j) * HW + 16 * s]      = xs[s][j]     + da;
            outb[(size_t)(32 + d0 + j) * HW + 16 * s] = xs[s][j + 8] + db;
        }
    }

    // one-hot scatter: one 1.0f per row (region pre-zeroed by memset)
    {
        int widx = winners[t];
        size_t row = (size_t)batch * 4096 + posblk + t;
        enc[row * 512 + widx] = 1.0f;
    }

    // ---- loss reduction ----
    double lsd = (double)ls;
    for (int off = 32; off; off >>= 1) lsd += __shfl_down(lsd, off, 64);
    if (l == 0) lred[wv] = lsd;
    __syncthreads();
    if (t == 0)
        atomicAdd(loss_acc, (lred[0] + lred[1]) + (lred[2] + lred[3]));

    int v0 = hc[t], v1 = hc[t + 256];
    if (v0) atomicAdd(&counts[t], v0);
    if (v1) atomicAdd(&counts[t + 256], v1);
}

__global__ __launch_bounds__(512) void vq_fin(const int* __restrict__ counts,
                                              const double* __restrict__ loss_acc,
                                              float* __restrict__ out) {
    __shared__ double red[512];
    int k = threadIdx.x;
    double p = (double)counts[k] * (1.0 / 131072.0);
    red[k] = p * log(p + 1e-10);
    __syncthreads();
    for (int s = 256; s; s >>= 1) {
        if (k < s) red[k] += red[k + s];
        __syncthreads();
    }
    if (k == 0) {
        out[PERPOFF] = (float)exp(-red[0]);
        out[0] = (float)(loss_acc[0] * 1.25 / 8388608.0);
    }
}

extern "C" void kernel_launch(void* const* d_in, const int* in_sizes, int n_in,
                              void* d_out, int out_size, void* d_ws, size_t ws_size,
                              hipStream_t stream) {
    const float* x  = (const float*)d_in[0];
    const float* wt = (const float*)d_in[1];
    float* out = (float*)d_out;
    char* ws = (char*)d_ws;

    int*            counts = (int*)ws;
    double*         loss   = (double*)(ws + 2048);
    float*          bias   = (float*)(ws + 4096);
    unsigned short* wbf    = (unsigned short*)(ws + 8192);
    float*          enc    = out + ENCOFF;

    vq_prep<<<512, 64, 0, stream>>>(wt, bias, wbf, counts, loss);
    // zero the one-hot region (268435456 B); assign scatters the 1.0s
    hipMemsetAsync((void*)enc, 0, (size_t)NVEC * 512 * sizeof(float), stream);
    vq_assign<<<512, 256, 0, stream>>>(x, wt, bias, wbf, out, enc, counts, loss);
    vq_fin<<<1, 512, 0, stream>>>(counts, loss, out);
}

// Round 6
// 95.071 us; speedup vs baseline: 4.3048x; 1.0578x over previous
//
#include <hip/hip_runtime.h>

typedef short   bf16x8 __attribute__((ext_vector_type(8)));
typedef float   f32x4  __attribute__((ext_vector_type(4)));

#define NVEC   131072      // 32*64*64 vectors
#define HW     4096
#define CHW    262144
#define QOFF   1
#define PERPOFF 8388609
#define ENCOFF  8388610

// ws layout: counts[512] @0, double loss @2048, float bias[512] @4096,
//            ushort wbf[512*64] @8192 (64 KB)

__device__ inline unsigned short f2bf(float f) {   // RTNE float->bf16
    unsigned int u = __float_as_uint(f);
    u += 0x7fffu + ((u >> 16) & 1u);
    return (unsigned short)(u >> 16);
}

// per code: bf16 copy of W + bias = -0.5*||w||^2 (f32-exact).
// Block 0 additionally zeroes counts + loss.
__global__ __launch_bounds__(64) void vq_prep(const float* __restrict__ wt,
                                              float* __restrict__ bias,
                                              unsigned short* __restrict__ wbf,
                                              int* __restrict__ counts,
                                              double* __restrict__ loss) {
    int c = blockIdx.x, d = threadIdx.x;
    if (c == 0) {
#pragma unroll
        for (int i = 0; i < 8; ++i) counts[d * 8 + i] = 0;
        if (d == 0) loss[0] = 0.0;
    }
    float v = wt[c * 64 + d];
    wbf[c * 64 + d] = f2bf(v);
    float s = v * v;
    for (int off = 32; off; off >>= 1) s += __shfl_down(s, off, 64);
    if (d == 0) bias[c] = -0.5f * s;
}

// 512 blocks x 512 threads (8 waves). Wave handles 32 rows: 2 row-sets of 16.
// Scores via mfma_f32_16x16x32_bf16 with C preloaded = -wsq/2; argmax.
// One-hot region pre-zeroed by memset; we scatter the 1.0s here.
__global__ __launch_bounds__(512) void vq_assign(
    const float* __restrict__ x, const float* __restrict__ wt,
    const float* __restrict__ bias, const unsigned short* __restrict__ wbf,
    float* __restrict__ out, float* __restrict__ enc,
    int* __restrict__ counts, double* __restrict__ loss_acc)
{
    __shared__ unsigned short wl[512 * 64];   // 64 KB, XOR-swizzled rows
    __shared__ float  biasl[512];
    __shared__ int    hc[512];
    __shared__ int    winners[256];
    __shared__ double lred[8];

    const int t = threadIdx.x, b = blockIdx.x;
    const int batch  = b >> 4;
    const int posblk = (b & 15) << 8;

    // ---- stage W bf16 into LDS with st-swizzle (row c: byte ^= (c&7)<<4) ----
    {
        const ulonglong2* src = (const ulonglong2*)wbf;   // 16B units
#pragma unroll
        for (int i = 0; i < 8; ++i) {
            int u  = t + 512 * i;          // 16B-unit index, 0..4095
            int c  = u >> 3;               // code row
            int bo = (u & 7) << 4;         // byte-in-row
            ulonglong2 v = src[u];
            *(ulonglong2*)((char*)wl + ((c << 7) | (bo ^ ((c & 7) << 4)))) = v;
        }
        biasl[t] = bias[t];
        hc[t] = 0;
    }
    __syncthreads();

    const int wv = t >> 6, l = t & 63;
    const int g  = l >> 4, cl = l & 15;
    const int posw = posblk + (wv << 5);      // this wave's 32 pos
    const int d0 = g << 3;

    // ---- load X f32 directly in A-fragment layout ----
    // lane: pos = posw + 16s + cl, d in {d0..d0+7} u {32+d0..32+d0+7}
    float xs[2][16];
    const float* xb = x + (size_t)batch * CHW + posw + cl;
#pragma unroll
    for (int s = 0; s < 2; ++s)
#pragma unroll
        for (int j = 0; j < 8; ++j) {
            xs[s][j]     = xb[(size_t)(d0 + j) * HW + 16 * s];
            xs[s][j + 8] = xb[(size_t)(32 + d0 + j) * HW + 16 * s];
        }

    bf16x8 af[2][2];
#pragma unroll
    for (int s = 0; s < 2; ++s)
#pragma unroll
        for (int h = 0; h < 2; ++h)
#pragma unroll
            for (int i = 0; i < 8; ++i)
                af[s][h][i] = (short)f2bf(xs[s][8 * h + i]);

    // ---- score loop: 32 col-tiles of 16 codes ----
    float best[2][4]; int bidx[2][4];
#pragma unroll
    for (int s = 0; s < 2; ++s)
#pragma unroll
        for (int i = 0; i < 4; ++i) { best[s][i] = -1e30f; bidx[s][i] = 0; }

    const char* wlb = (const char*)wl;
#pragma unroll 4
    for (int tt = 0; tt < 32; ++tt) {
        int c  = (tt << 4) + cl;
        int rb = c << 7;
        int sw = (c & 7) << 4;
        bf16x8 b0 = *(const bf16x8*)(wlb + (rb | ((16 * g) ^ sw)));
        bf16x8 b1 = *(const bf16x8*)(wlb + (rb | ((64 + 16 * g) ^ sw)));
        float bs = biasl[c];
#pragma unroll
        for (int s = 0; s < 2; ++s) {
            f32x4 acc = {bs, bs, bs, bs};
            acc = __builtin_amdgcn_mfma_f32_16x16x32_bf16(af[s][0], b0, acc, 0, 0, 0);
            acc = __builtin_amdgcn_mfma_f32_16x16x32_bf16(af[s][1], b1, acc, 0, 0, 0);
#pragma unroll
            for (int i = 0; i < 4; ++i)
                if (acc[i] > best[s][i]) { best[s][i] = acc[i]; bidx[s][i] = c; }
        }
    }

    // ---- 16-lane butterfly argmax (tie -> smaller index) ----
#pragma unroll
    for (int s = 0; s < 2; ++s)
#pragma unroll
        for (int i = 0; i < 4; ++i) {
            float bd = best[s][i]; int bi = bidx[s][i];
#pragma unroll
            for (int off = 1; off < 16; off <<= 1) {
                float od = __shfl_xor(bd, off, 64);
                int   oi = __shfl_xor(bi, off, 64);
                if (od > bd || (od == bd && oi < bi)) { bd = od; bi = oi; }
            }
            bidx[s][i] = bi;
        }

    // winners to LDS (row-in-wave = 16s + 4g + i), + histogram
    if (cl == 0) {
#pragma unroll
        for (int s = 0; s < 2; ++s)
#pragma unroll
            for (int i = 0; i < 4; ++i) {
                int w = bidx[s][i];
                winners[(wv << 5) + (s << 4) + (g << 2) + i] = w;
                atomicAdd(&hc[w], 1);
            }
    }
    __syncthreads();

    // ---- epilogue: quantized_st + loss (f32-exact) ----
    float* outb = out + QOFF + (size_t)batch * CHW + posw + cl;
    float ls = 0.f;
#pragma unroll
    for (int s = 0; s < 2; ++s) {
        int widx = winners[(wv << 5) + (s << 4) + cl];
        float q[16];
        *(float4*)&q[0]  = *(const float4*)(wt + widx * 64 + d0);
        *(float4*)&q[4]  = *(const float4*)(wt + widx * 64 + d0 + 4);
        *(float4*)&q[8]  = *(const float4*)(wt + widx * 64 + 32 + d0);
        *(float4*)&q[12] = *(const float4*)(wt + widx * 64 + 32 + d0 + 4);
#pragma unroll
        for (int j = 0; j < 8; ++j) {
            float da = q[j]     - xs[s][j];
            float db = q[j + 8] - xs[s][j + 8];
            ls += da * da + db * db;
            outb[(size_t)(d0 + j) * HW + 16 * s]      = xs[s][j]     + da;
            outb[(size_t)(32 + d0 + j) * HW + 16 * s] = xs[s][j + 8] + db;
        }
    }

    // one-hot scatter: one 1.0f per row (region pre-zeroed by memset)
    if (t < 256) {
        int widx = winners[t];
        size_t row = (size_t)batch * 4096 + posblk + t;
        enc[row * 512 + widx] = 1.0f;
    }

    // ---- loss reduction ----
    double lsd = (double)ls;
    for (int off = 32; off; off >>= 1) lsd += __shfl_down(lsd, off, 64);
    if (l == 0) lred[wv] = lsd;
    __syncthreads();
    if (t == 0) {
        double s = 0.0;
#pragma unroll
        for (int i = 0; i < 8; ++i) s += lred[i];
        atomicAdd(loss_acc, s);
    }

    int v0 = hc[t];
    if (v0) atomicAdd(&counts[t], v0);
}

__global__ __launch_bounds__(512) void vq_fin(const int* __restrict__ counts,
                                              const double* __restrict__ loss_acc,
                                              float* __restrict__ out) {
    __shared__ double red[512];
    int k = threadIdx.x;
    double p = (double)counts[k] * (1.0 / 131072.0);
    red[k] = p * log(p + 1e-10);
    __syncthreads();
    for (int s = 256; s; s >>= 1) {
        if (k < s) red[k] += red[k + s];
        __syncthreads();
    }
    if (k == 0) {
        out[PERPOFF] = (float)exp(-red[0]);
        out[0] = (float)(loss_acc[0] * 1.25 / 8388608.0);
    }
}

extern "C" void kernel_launch(void* const* d_in, const int* in_sizes, int n_in,
                              void* d_out, int out_size, void* d_ws, size_t ws_size,
                              hipStream_t stream) {
    const float* x  = (const float*)d_in[0];
    const float* wt = (const float*)d_in[1];
    float* out = (float*)d_out;
    char* ws = (char*)d_ws;

    int*            counts = (int*)ws;
    double*         loss   = (double*)(ws + 2048);
    float*          bias   = (float*)(ws + 4096);
    unsigned short* wbf    = (unsigned short*)(ws + 8192);
    float*          enc    = out + ENCOFF;

    vq_prep<<<512, 64, 0, stream>>>(wt, bias, wbf, counts, loss);
    // zero the one-hot region (268435456 B); assign scatters the 1.0s
    hipMemsetAsync((void*)enc, 0, (size_t)NVEC * 512 * sizeof(float), stream);
    vq_assign<<<512, 512, 0, stream>>>(x, wt, bias, wbf, out, enc, counts, loss);
    vq_fin<<<1, 512, 0, stream>>>(counts, loss, out);
}